// Round 7
// baseline (779.530 us; speedup 1.0000x reference)
//
#include <hip/hip_runtime.h>
#include <math.h>

#define KSIZE 7
#define C_CH  256
#define HW    256
#define BATCH 8

#define TH    32            // output rows per tile
#define ROWS  (TH + 6)      // 38 input rows staged (3-row halo each side)
#define LDW   264           // 4 zero + 256 + 4 zero padded floats per LDS row
#define NT    (HW / TH)     // 8 tiles per (n,c) plane

// ---------------------------------------------------------------------------
// Kernel 1: synthesize the 256 x 7 x 7 Gabor filter bank into d_ws.
// ---------------------------------------------------------------------------
__global__ void gabor_weights_kernel(const float* __restrict__ log_sigma,
                                     const float* __restrict__ log_freq,
                                     const float* __restrict__ theta,
                                     float* __restrict__ gw) {
    int c = threadIdx.x;
    if (c >= C_CH) return;
    float sigma = expf(log_sigma[c]);
    float freq  = expf(log_freq[c]);
    float ct = cosf(theta[c]);
    float st = sinf(theta[c]);
    float inv_sigma = 1.0f / sigma;
    float vals[KSIZE * KSIZE];
    float sum = 0.0f;
    #pragma unroll
    for (int i = 0; i < KSIZE; ++i) {
        #pragma unroll
        for (int j = 0; j < KSIZE; ++j) {
            float dx = (float)(i - 3);
            float dy = (float)(j - 3);
            float x0 = (dx * ct + dy * st) * inv_sigma;
            float x1 = (-dx * st + dy * ct) * inv_sigma;
            float g  = expf(-0.5f * (x0 * x0 + x1 * x1));
            float v  = g * cosf(6.283185307179586f * freq * x0);
            vals[i * KSIZE + j] = v;
            sum += v;
        }
    }
    float inv = 1.0f / sum;
    #pragma unroll
    for (int k = 0; k < KSIZE * KSIZE; ++k)
        gw[c * (KSIZE * KSIZE) + k] = vals[k] * inv;
}

// ---------------------------------------------------------------------------
// Kernel 2: depthwise 7x7 conv; persistent block per (n,c) plane; T14
// reg-staged pipeline (no global_load_lds => no DMA/LDS alias => compiler
// cannot couple compute's ds_reads to the in-flight prefetch):
//   [issue 8 global_load_dwordx4 -> g regs]  (next tile)
//   [halo LDS->LDS: rows 0..5 of next = rows 32..37 of cur]
//   [compute: 42 ds_read_b128 interleaved with 1568 FMAs]
//   [ds_write g -> next buffer]   <- compiler inserts COUNTED vmcnt here,
//                                    satisfied long ago under the compute
//   [8 output float4 stores]      <- fire-and-forget
//   [s_waitcnt lgkmcnt(0); s_barrier]  <- no vmcnt(0): stores stay in flight
// Out-of-image staged rows carry zeros in g, folding edge handling into the
// same ds_writes.  2 blocks/CU (2x78.4KB LDS), ~120 VGPR -> no spills.
// ---------------------------------------------------------------------------
template <int T>
__device__ __forceinline__ void conv_iter(float (&CURB)[ROWS][LDW],
                                          float (&NXTB)[ROWS][LDW],
                                          const float* __restrict__ xp,
                                          float* __restrict__ op,
                                          const float (&w)[KSIZE * KSIZE],
                                          int tid, int lane, int wv,
                                          int colp, int ob) {
    // ---- 1. issue next tile's fresh-row loads into registers (8 per thread)
    float4 g[8];
    if (T + 1 < NT) {
        const int row0 = (T + 1) * TH - 3;   // global row of next tile-row 0
        #pragma unroll
        for (int i = 0; i < 8; ++i) {
            const int rr = 6 + wv + 4 * i;   // tile rows 6..37
            const int gr = row0 + rr;
            if (T + 1 == NT - 1 && gr >= HW) {       // wave-uniform, last stage only
                g[i] = make_float4(0.f, 0.f, 0.f, 0.f);
            } else {
                g[i] = *reinterpret_cast<const float4*>(xp + (size_t)gr * HW + lane * 4);
            }
        }
    }

    // ---- 2. halo: rows 0..5 of next = rows 32..37 of current (LDS->LDS)
    if (T + 1 < NT) {
        #pragma unroll
        for (int i2 = 0; i2 < 2; ++i2) {
            const int idx = tid + i2 * 256;
            if (idx < 6 * 64) {              // wave-uniform (tid<128 on 2nd pass)
                const int r2 = idx >> 6, q2 = idx & 63;
                *reinterpret_cast<float4*>(&NXTB[r2][4 + q2 * 4]) =
                    *reinterpret_cast<const float4*>(&CURB[32 + r2][4 + q2 * 4]);
            }
        }
    }

    // ---- 3. compute 8 rows x 4 cols (ds_reads interleaved with FMAs)
    float acc[8][4];
    #pragma unroll
    for (int o = 0; o < 8; ++o)
        #pragma unroll
        for (int cc = 0; cc < 4; ++cc) acc[o][cc] = 0.f;

    #pragma unroll
    for (int r = 0; r < 14; ++r) {
        float4 a = *reinterpret_cast<const float4*>(&CURB[ob + r][colp]);
        float4 b = *reinterpret_cast<const float4*>(&CURB[ob + r][colp + 4]);
        float4 d = *reinterpret_cast<const float4*>(&CURB[ob + r][colp + 8]);
        float f[12] = {a.x, a.y, a.z, a.w, b.x, b.y, b.z, b.w, d.x, d.y, d.z, d.w};
        #pragma unroll
        for (int o = 0; o < 8; ++o) {
            if (o <= r && r <= o + 6) {      // compile-time after unroll
                const int ki = r - o;
                #pragma unroll
                for (int cc = 0; cc < 4; ++cc) {
                    #pragma unroll
                    for (int j = 0; j < KSIZE; ++j)
                        acc[o][cc] += f[cc + j + 1] * w[ki * KSIZE + j];
                }
            }
        }
    }

    // ---- 4. ds_write staged rows (counted vmcnt, already satisfied)
    if (T + 1 < NT) {
        #pragma unroll
        for (int i = 0; i < 8; ++i) {
            const int rr = 6 + wv + 4 * i;
            *reinterpret_cast<float4*>(&NXTB[rr][4 + lane * 4]) = g[i];
        }
    }

    // ---- 5. output stores (fire-and-forget)
    const int orow0 = T * TH + ob;
    #pragma unroll
    for (int o = 0; o < 8; ++o) {
        float4 v = make_float4(acc[o][0], acc[o][1], acc[o][2], acc[o][3]);
        *reinterpret_cast<float4*>(op + (size_t)(orow0 + o) * HW + colp) = v;
    }

    // ---- 6. barrier: only LDS needs draining; stores/loads keep flowing
    if (T + 1 < NT) {
        asm volatile("s_waitcnt lgkmcnt(0)" ::: "memory");
        __builtin_amdgcn_s_barrier();
    }
}

__global__ __launch_bounds__(256, 2)
void gabor_conv_kernel(const float* __restrict__ x,
                       const float* __restrict__ gw,
                       float* __restrict__ out) {
    __shared__ __align__(16) float tA[ROWS][LDW];
    __shared__ __align__(16) float tB[ROWS][LDW];

    const int tid  = threadIdx.x;
    const int lane = tid & 63;
    const int wv   = tid >> 6;
    const int c    = blockIdx.x;
    const int n    = blockIdx.y;

    const size_t plane = ((size_t)n * C_CH + c) * (size_t)(HW * HW);
    const float* xp = x + plane;
    float*       op = out + plane;

    // ---- zero the pad columns of BOTH buffers once
    for (int idx = tid; idx < 2 * ROWS; idx += 256) {
        int b  = idx / ROWS;
        int rr = idx - b * ROWS;
        float4 z = make_float4(0.f, 0.f, 0.f, 0.f);
        if (b == 0) {
            *reinterpret_cast<float4*>(&tA[rr][0])   = z;
            *reinterpret_cast<float4*>(&tA[rr][260]) = z;
        } else {
            *reinterpret_cast<float4*>(&tB[rr][0])   = z;
            *reinterpret_cast<float4*>(&tB[rr][260]) = z;
        }
    }

    // ---- weights (block-uniform)
    float w[KSIZE * KSIZE];
    const float* wp = gw + c * (KSIZE * KSIZE);
    #pragma unroll
    for (int k = 0; k < KSIZE * KSIZE; ++k) w[k] = wp[k];

    // ---- prologue: tile 0 into tA (rows 0..2 zero, rows 3..37 copied)
    for (int i = tid; i < 3 * 64; i += 256) {
        int r = i >> 6, q = i & 63;
        *reinterpret_cast<float4*>(&tA[r][4 + q * 4]) = make_float4(0.f, 0.f, 0.f, 0.f);
    }
    for (int rr = 3 + wv; rr < ROWS; rr += 4) {
        float4 v = *reinterpret_cast<const float4*>(xp + (size_t)(rr - 3) * HW + lane * 4);
        *reinterpret_cast<float4*>(&tA[rr][4 + lane * 4]) = v;
    }
    asm volatile("s_waitcnt lgkmcnt(0)" ::: "memory");
    __builtin_amdgcn_s_barrier();

    const int colp = lane * 4;
    const int ob   = wv * 8;

    conv_iter<0>(tA, tB, xp, op, w, tid, lane, wv, colp, ob);
    conv_iter<1>(tB, tA, xp, op, w, tid, lane, wv, colp, ob);
    conv_iter<2>(tA, tB, xp, op, w, tid, lane, wv, colp, ob);
    conv_iter<3>(tB, tA, xp, op, w, tid, lane, wv, colp, ob);
    conv_iter<4>(tA, tB, xp, op, w, tid, lane, wv, colp, ob);
    conv_iter<5>(tB, tA, xp, op, w, tid, lane, wv, colp, ob);
    conv_iter<6>(tA, tB, xp, op, w, tid, lane, wv, colp, ob);
    conv_iter<7>(tB, tA, xp, op, w, tid, lane, wv, colp, ob);
}

extern "C" void kernel_launch(void* const* d_in, const int* in_sizes, int n_in,
                              void* d_out, int out_size, void* d_ws, size_t ws_size,
                              hipStream_t stream) {
    const float* x  = (const float*)d_in[0];
    const float* ls = (const float*)d_in[1];
    const float* lf = (const float*)d_in[2];
    const float* th = (const float*)d_in[3];
    float* out = (float*)d_out;
    float* gw  = (float*)d_ws;   // 256*49*4 = 50176 bytes of scratch

    gabor_weights_kernel<<<1, 256, 0, stream>>>(ls, lf, th, gw);

    dim3 grid(C_CH, BATCH);      // one persistent block per (n,c) plane
    gabor_conv_kernel<<<grid, 256, 0, stream>>>(x, gw, out);
}

// Round 8
// 739.070 us; speedup vs baseline: 1.0547x; 1.0547x over previous
//
#include <hip/hip_runtime.h>
#include <math.h>

#define KSIZE 7
#define C_CH  256
#define HW    256
#define BATCH 8

#define SLOTS 16            // circular row buffer depth (per wave)
#define SW    272           // floats per slot row: 4 left pad + 256 + 12 pad
#define NSTEP 32            // 32 steps x 8 output rows = 256 rows

// ---------------------------------------------------------------------------
// Kernel 1: synthesize the 256 x 7 x 7 Gabor filter bank into d_ws.
// ---------------------------------------------------------------------------
__global__ void gabor_weights_kernel(const float* __restrict__ log_sigma,
                                     const float* __restrict__ log_freq,
                                     const float* __restrict__ theta,
                                     float* __restrict__ gw) {
    int c = threadIdx.x;
    if (c >= C_CH) return;
    float sigma = expf(log_sigma[c]);
    float freq  = expf(log_freq[c]);
    float ct = cosf(theta[c]);
    float st = sinf(theta[c]);
    float inv_sigma = 1.0f / sigma;
    float vals[KSIZE * KSIZE];
    float sum = 0.0f;
    #pragma unroll
    for (int i = 0; i < KSIZE; ++i) {
        #pragma unroll
        for (int j = 0; j < KSIZE; ++j) {
            float dx = (float)(i - 3);
            float dy = (float)(j - 3);
            float x0 = (dx * ct + dy * st) * inv_sigma;
            float x1 = (-dx * st + dy * ct) * inv_sigma;
            float g  = expf(-0.5f * (x0 * x0 + x1 * x1));
            float v  = g * cosf(6.283185307179586f * freq * x0);
            vals[i * KSIZE + j] = v;
            sum += v;
        }
    }
    float inv = 1.0f / sum;
    #pragma unroll
    for (int k = 0; k < KSIZE * KSIZE; ++k)
        gw[c * (KSIZE * KSIZE) + k] = vals[k] * inv;
}

// ---------------------------------------------------------------------------
// Kernel 2: depthwise 7x7 conv; ONE WAVE per (n,c) plane; zero barriers.
// Per-wave 16-slot circular row buffer in LDS (slot(row) = (row+3)&15).
// Step s (output rows 8s..8s+7, window rows 8s-3..8s+10 = slots BASE..BASE+13,
// BASE = (8s)&15 static per parity):
//   vmcnt(8)                      -> all prior gloads landed; stores in flight
//   early PF rows 8s+11,12        -> free slots BASE+14,15
//   42 ds_read_b128 + 1568 FMA    (static slot offsets; per-wave, no barrier)
//   lgkmcnt(0)                    -> reads complete before slot overwrite
//   late PF rows 8s+13..18        -> slots BASE..BASE+5 (just consumed)
//   8 output float4 stores        -> fire-and-forget
// vmcnt(8) at next step drains exactly the <=8 gloads (issued before the 8
// stores), never the stores.  Rows >=256 prefetch as ds_write zeros (these
// don't bump vmcnt; count logic still drains all gloads).  Every input row
// fetched exactly once.  2 blocks/CU (69.6KB LDS), waves fully independent.
// ---------------------------------------------------------------------------
__device__ __forceinline__ void gload_lds16(const float* g, float* l) {
    __builtin_amdgcn_global_load_lds(
        (const __attribute__((address_space(1))) void*)g,
        (__attribute__((address_space(3))) void*)l,
        16, 0, 0);
}

// prefetch row -> slot (wave-uniform row; zero-fill past bottom edge)
__device__ __forceinline__ void pf_row(float (*B)[SW], const float* xp,
                                       int row, int slot, int lane) {
    if (row < HW) {
        gload_lds16(xp + (size_t)row * HW + lane * 4, &B[slot][4]);
    } else {
        *reinterpret_cast<float4*>(&B[slot][4 + lane * 4]) =
            make_float4(0.f, 0.f, 0.f, 0.f);
    }
}

template <int BASE>   // (8*s) & 15 : 0 for even steps, 8 for odd
__device__ __forceinline__ void conv_step(float (*B)[SW],
                                          const float* __restrict__ xp,
                                          float* __restrict__ op,
                                          const float (&w)[KSIZE * KSIZE],
                                          int s, int lane) {
    // 1. boundary: drain ALL outstanding gloads (oldest), keep stores afloat
    asm volatile("s_waitcnt vmcnt(8)" ::: "memory");

    // 2. early prefetch into the 2 free slots
    pf_row(B, xp, 8 * s + 11, (BASE + 14) & 15, lane);
    pf_row(B, xp, 8 * s + 12, (BASE + 15) & 15, lane);

    // 3. compute 8 rows x 4 cols (reads slots BASE..BASE+13; disjoint from
    //    the early-PF dest slots, so no wait couples them)
    float acc[8][4];
    #pragma unroll
    for (int o = 0; o < 8; ++o)
        #pragma unroll
        for (int cc = 0; cc < 4; ++cc) acc[o][cc] = 0.f;

    #pragma unroll
    for (int r = 0; r < 14; ++r) {
        const int slot = (BASE + r) & 15;
        float4 a = *reinterpret_cast<const float4*>(&B[slot][lane * 4]);
        float4 b = *reinterpret_cast<const float4*>(&B[slot][lane * 4 + 4]);
        float4 d = *reinterpret_cast<const float4*>(&B[slot][lane * 4 + 8]);
        float f[12] = {a.x, a.y, a.z, a.w, b.x, b.y, b.z, b.w, d.x, d.y, d.z, d.w};
        #pragma unroll
        for (int o = 0; o < 8; ++o) {
            if (o <= r && r <= o + 6) {      // compile-time after unroll
                const int ki = r - o;
                #pragma unroll
                for (int cc = 0; cc < 4; ++cc) {
                    #pragma unroll
                    for (int j = 0; j < KSIZE; ++j)
                        acc[o][cc] += f[cc + j + 1] * w[ki * KSIZE + j];
                }
            }
        }
    }

    // 4. reads complete before their slots are overwritten by DMA
    asm volatile("s_waitcnt lgkmcnt(0)" ::: "memory");

    // 5. late prefetch into the just-consumed slots BASE..BASE+5
    #pragma unroll
    for (int i = 0; i < 6; ++i)
        pf_row(B, xp, 8 * s + 13 + i, (BASE + 16 + i) & 15, lane);

    // 6. output stores (issued after all gloads -> vmcnt(8) never waits on them)
    #pragma unroll
    for (int o = 0; o < 8; ++o) {
        float4 v = make_float4(acc[o][0], acc[o][1], acc[o][2], acc[o][3]);
        *reinterpret_cast<float4*>(op + (size_t)(8 * s + o) * HW + lane * 4) = v;
    }
}

__global__ __launch_bounds__(256, 2)
void gabor_conv_kernel(const float* __restrict__ x,
                       const float* __restrict__ gw,
                       float* __restrict__ out) {
    __shared__ __align__(16) float buf[4][SLOTS][SW];   // 69632 B

    const int tid  = threadIdx.x;
    const int lane = tid & 63;
    const int wv   = tid >> 6;
    const int p    = blockIdx.x * 4 + wv;     // plane id 0..2047
    const int c    = p & (C_CH - 1);

    const size_t plane = (size_t)p * (HW * HW);
    const float* xp = x + plane;
    float*       op = out + plane;
    float (*B)[SW] = buf[wv];

    // ---- weights: pin to SGPRs (wave-uniform)
    float w[KSIZE * KSIZE];
    const float* wp = gw + c * (KSIZE * KSIZE);
    #pragma unroll
    for (int k = 0; k < KSIZE * KSIZE; ++k) {
        int wi = __builtin_amdgcn_readfirstlane(__float_as_int(wp[k]));
        w[k] = __int_as_float(wi);
    }

    // ---- zero pads of all 16 slots (cols 0..3 and 260..271), lanes 0..15
    if (lane < SLOTS) {
        float4 z = make_float4(0.f, 0.f, 0.f, 0.f);
        *reinterpret_cast<float4*>(&B[lane][0])   = z;
        *reinterpret_cast<float4*>(&B[lane][260]) = z;
        *reinterpret_cast<float4*>(&B[lane][264]) = z;
        *reinterpret_cast<float4*>(&B[lane][268]) = z;
    }
    // ---- top halo rows -3..-1 -> slots 0..2 interior zeros
    {
        float4 z = make_float4(0.f, 0.f, 0.f, 0.f);
        *reinterpret_cast<float4*>(&B[0][4 + lane * 4]) = z;
        *reinterpret_cast<float4*>(&B[1][4 + lane * 4]) = z;
        *reinterpret_cast<float4*>(&B[2][4 + lane * 4]) = z;
    }
    // ---- rows 0..10 -> slots 3..13
    #pragma unroll
    for (int r = 0; r < 11; ++r)
        gload_lds16(xp + (size_t)r * HW + lane * 4, &B[3 + r][4]);
    asm volatile("s_waitcnt vmcnt(0) lgkmcnt(0)" ::: "memory");

    // ---- 32 steps, rolled loop (parity-static LDS offsets)
    for (int sp = 0; sp < NSTEP / 2; ++sp) {
        conv_step<0>(B, xp, op, w, 2 * sp,     lane);
        conv_step<8>(B, xp, op, w, 2 * sp + 1, lane);
    }
}

extern "C" void kernel_launch(void* const* d_in, const int* in_sizes, int n_in,
                              void* d_out, int out_size, void* d_ws, size_t ws_size,
                              hipStream_t stream) {
    const float* x  = (const float*)d_in[0];
    const float* ls = (const float*)d_in[1];
    const float* lf = (const float*)d_in[2];
    const float* th = (const float*)d_in[3];
    float* out = (float*)d_out;
    float* gw  = (float*)d_ws;   // 256*49*4 = 50176 bytes of scratch

    gabor_weights_kernel<<<1, 256, 0, stream>>>(ls, lf, th, gw);

    gabor_conv_kernel<<<BATCH * C_CH / 4, 256, 0, stream>>>(x, gw, out);
}

// Round 9
// 313.472 us; speedup vs baseline: 2.4868x; 2.3577x over previous
//
#include <hip/hip_runtime.h>
#include <math.h>

#define KSIZE 7
#define C_CH  256
#define HW    256
#define BATCH 8

#define TH    32            // output rows per block
#define ROWS  (TH + 6)      // 38 input rows staged (3-row halo each side)
#define SEGW  68            // words per row per segment (66 used + 2 slack)
#define NQ    (ROWS * 66)   // staged quads: 66 per row (1 zero + 64 data + 1 zero)

// ---------------------------------------------------------------------------
// Kernel 1: synthesize the 256 x 7 x 7 Gabor filter bank into d_ws.
// ---------------------------------------------------------------------------
__global__ void gabor_weights_kernel(const float* __restrict__ log_sigma,
                                     const float* __restrict__ log_freq,
                                     const float* __restrict__ theta,
                                     float* __restrict__ gw) {
    int c = threadIdx.x;
    if (c >= C_CH) return;
    float sigma = expf(log_sigma[c]);
    float freq  = expf(log_freq[c]);
    float ct = cosf(theta[c]);
    float st = sinf(theta[c]);
    float inv_sigma = 1.0f / sigma;
    float vals[KSIZE * KSIZE];
    float sum = 0.0f;
    #pragma unroll
    for (int i = 0; i < KSIZE; ++i) {
        #pragma unroll
        for (int j = 0; j < KSIZE; ++j) {
            float dx = (float)(i - 3);
            float dy = (float)(j - 3);
            float x0 = (dx * ct + dy * st) * inv_sigma;
            float x1 = (-dx * st + dy * ct) * inv_sigma;
            float g  = expf(-0.5f * (x0 * x0 + x1 * x1));
            float v  = g * cosf(6.283185307179586f * freq * x0);
            vals[i * KSIZE + j] = v;
            sum += v;
        }
    }
    float inv = 1.0f / sum;
    #pragma unroll
    for (int k = 0; k < KSIZE * KSIZE; ++k)
        gw[c * (KSIZE * KSIZE) + k] = vals[k] * inv;
}

// ---------------------------------------------------------------------------
// Kernel 2: depthwise 7x7 conv, R1 structure (stage -> barrier -> compute ->
// store) with a DWORD-DEINTERLEAVED LDS layout to kill the 8-way dword-phase
// bank conflicts of lane-stride-16B ds_read_b128 (R6-R8: 6.3e7 conflict
// cycles, ~23/instr).  seg[s][row][k] holds padded col 4k+s, so every
// compute read is  seg[m&3][row][lane + (m>>2)]  -- per-lane stride 4B,
// <=2 lanes/bank, conflict-free (m136).  Staging scatters each global
// float4 into 4 ds_write_b32 (also stride-4B dense).
// ---------------------------------------------------------------------------
__global__ __launch_bounds__(256, 3)
void gabor_conv_kernel(const float* __restrict__ x,
                       const float* __restrict__ gw,
                       float* __restrict__ out) {
    __shared__ float seg[4][ROWS][SEGW];   // 41,344 B -> 3 blocks/CU

    const int tid = threadIdx.x;
    const int ht  = blockIdx.x;   // 0..7   row tile
    const int c   = blockIdx.y;   // 0..255
    const int n   = blockIdx.z;   // 0..7

    const size_t plane = ((size_t)n * C_CH + c) * (size_t)(HW * HW);
    const float* xp = x + plane;
    float*       op = out + plane;
    const int row0 = ht * TH - 3;   // image row of LDS row 0

    // ---- stage global -> LDS, deinterleaving dwords into 4 segments.
    // quad q covers padded cols 4q..4q+3 (padded col = col + 4);
    // q==0 and q==65 are the zero pads, out-of-image rows are zeros.
    for (int idx = tid; idx < NQ; idx += 256) {
        int rr = idx / 66;
        int q  = idx - rr * 66;
        float4 v = make_float4(0.f, 0.f, 0.f, 0.f);
        int gr = row0 + rr;
        if (q >= 1 && q <= 64 && gr >= 0 && gr < HW) {
            v = *reinterpret_cast<const float4*>(xp + (size_t)gr * HW + (q - 1) * 4);
        }
        seg[0][rr][q] = v.x;
        seg[1][rr][q] = v.y;
        seg[2][rr][q] = v.z;
        seg[3][rr][q] = v.w;
    }

    // ---- weights: block-uniform loads
    float w[KSIZE * KSIZE];
    const float* wp = gw + c * (KSIZE * KSIZE);
    #pragma unroll
    for (int k = 0; k < KSIZE * KSIZE; ++k) w[k] = wp[k];

    __syncthreads();

    const int lane = tid & 63;    // output cols 4*lane .. 4*lane+3
    const int wv   = tid >> 6;    // output rows ob..ob+7 of the tile
    const int ob   = wv * 8;

    float acc[8][4];
    #pragma unroll
    for (int o = 0; o < 8; ++o)
        #pragma unroll
        for (int cc = 0; cc < 4; ++cc) acc[o][cc] = 0.f;

    #pragma unroll
    for (int r = 0; r < 14; ++r) {      // LDS rows ob..ob+13
        const int rw = ob + r;
        // window value m (padded col 4*lane+m), m = 1..10:
        //   f[m] = seg[m&3][rw][lane + (m>>2)]   (stride-4B dense reads)
        float f[11];
        #pragma unroll
        for (int m = 1; m <= 10; ++m)
            f[m] = seg[m & 3][rw][lane + (m >> 2)];

        #pragma unroll
        for (int o = 0; o < 8; ++o) {
            if (o <= r && r <= o + 6) {     // compile-time after unroll
                const int ki = r - o;        // kernel row index 0..6
                #pragma unroll
                for (int cc = 0; cc < 4; ++cc) {
                    #pragma unroll
                    for (int j = 0; j < KSIZE; ++j)
                        acc[o][cc] += f[cc + j + 1] * w[ki * KSIZE + j];
                }
            }
        }
    }

    // ---- write 8 rows x float4, fully coalesced
    const int orow0 = ht * TH + ob;
    #pragma unroll
    for (int o = 0; o < 8; ++o) {
        float4 v = make_float4(acc[o][0], acc[o][1], acc[o][2], acc[o][3]);
        *reinterpret_cast<float4*>(op + (size_t)(orow0 + o) * HW + lane * 4) = v;
    }
}

extern "C" void kernel_launch(void* const* d_in, const int* in_sizes, int n_in,
                              void* d_out, int out_size, void* d_ws, size_t ws_size,
                              hipStream_t stream) {
    const float* x  = (const float*)d_in[0];
    const float* ls = (const float*)d_in[1];
    const float* lf = (const float*)d_in[2];
    const float* th = (const float*)d_in[3];
    float* out = (float*)d_out;
    float* gw  = (float*)d_ws;   // 256*49*4 = 50176 bytes of scratch

    gabor_weights_kernel<<<1, 256, 0, stream>>>(ls, lf, th, gw);

    dim3 grid(HW / TH, C_CH, BATCH);
    gabor_conv_kernel<<<grid, 256, 0, stream>>>(x, gw, out);
}